// Round 1
// baseline (292.086 us; speedup 1.0000x reference)
//
#include <hip/hip_runtime.h>

// ---------------------------------------------------------------------------
// Fused MHA forward on MI355X (gfx950), bf16 MFMA path, round 8.
// B=8, N=1024, C=1024, H=16, D=64.  M = B*N = 8192.
// ws (64 MB): [0,16M) xb then ob (xb dead after qkv_gemm)
//             [16,32M) qb  [32,48M) kb  [48,64M) vbT        (all bf16)
// d_out (32 MB): [0,6M) winb; [6M,8M) woutb — scratch, dead before out_gemm.
// NEW vs round 7:
//  * attn: swapped QK^T (S^T = MFMA(K,Q)) -> per-lane q is lane-local:
//    float4 mask loads, 4x ds_write_b64 for P^T (was 16x b16), scalar
//    row-sum, packed 8B output stores. Same LDS panel reads, same MFMA count.
//  * qkv_gemm writes V directly transposed (bh,d,seq) -> transpose_v deleted.
// ---------------------------------------------------------------------------

typedef __bf16 bf16x8 __attribute__((ext_vector_type(8)));
typedef float f32x4 __attribute__((ext_vector_type(4)));
typedef unsigned short us4v __attribute__((ext_vector_type(4)));

#define MFMA16 __builtin_amdgcn_mfma_f32_16x16x32_bf16

__device__ __forceinline__ unsigned short f2bf(float f) {
    return __builtin_bit_cast(unsigned short, (__bf16)f);   // native cvt, RNE
}

__device__ __forceinline__ us4v cvt4(float4 v) {
    us4v r;
    r.x = f2bf(v.x); r.y = f2bf(v.y); r.z = f2bf(v.z); r.w = f2bf(v.w);
    return r;
}

// async global->LDS, 16 B per lane; LDS dest = wave-uniform base + lane*16
__device__ __forceinline__ void gl16(const unsigned short* g, unsigned short* l) {
    __builtin_amdgcn_global_load_lds(
        (const __attribute__((address_space(1))) unsigned*)g,
        (__attribute__((address_space(3))) unsigned*)l, 16, 0, 0);
}

// ---------------------------------------------------------------------------
// Kernel 0: fp32 -> bf16 convert (one float4 per thread)
// ---------------------------------------------------------------------------
__global__ __launch_bounds__(256)
void cvt_bf16(const float* __restrict__ src, unsigned short* __restrict__ dst,
              int n4) {
    const int i = blockIdx.x * 256 + threadIdx.x;
    if (i < n4) {
        float4 v = ((const float4*)src)[i];
        ((us4v*)dst)[i] = cvt4(v);
    }
}

// ---------------------------------------------------------------------------
// Kernel 1: qkv = xb @ winb^T + b_in -> q (x0.125), k in (B,H,N,D) bf16,
//           V written directly transposed as vbT (B,H,D,N) bf16.
// Swizzled-chunk staging + fragment reads (2-way banks).
// ---------------------------------------------------------------------------
__global__ __launch_bounds__(256, 3)
void qkv_gemm(const unsigned short* __restrict__ xb,   // (8192,1024) bf16
              const unsigned short* __restrict__ wb,   // (3072,1024) bf16
              const float* __restrict__ bias,
              unsigned short* __restrict__ qb, unsigned short* __restrict__ kb,
              unsigned short* __restrict__ vbT)
{
    __shared__ unsigned short lsa[128 * 32];
    __shared__ unsigned short lsb[128 * 32];
    const int tid  = threadIdx.x;
    const int wave = tid >> 6, lane = tid & 63;
    const int quad = lane >> 4, l15 = lane & 15;
    const int rch = (quad ^ ((l15 >> 1) & 3)) * 8;   // swizzled read chunk
    const int m0 = blockIdx.x * 128, n0 = blockIdx.y * 128;
    const int wm = (wave & 1) * 64, wn = (wave >> 1) * 64;

    const int srow = wave * 32 + (lane >> 2);
    const int scol = ((lane & 3) ^ ((lane >> 3) & 3)) * 8;   // swizzled stage
    const unsigned short* ga = xb + (size_t)(m0 + srow) * 1024 + scol;
    const unsigned short* gb = wb + (size_t)(n0 + srow) * 1024 + scol;
    unsigned short* la0 = &lsa[(wave * 32) * 32];
    unsigned short* la1 = &lsa[(wave * 32 + 16) * 32];
    unsigned short* lb0 = &lsb[(wave * 32) * 32];
    unsigned short* lb1 = &lsb[(wave * 32 + 16) * 32];

    f32x4 acc[4][4];
#pragma unroll
    for (int i = 0; i < 4; ++i)
#pragma unroll
        for (int j = 0; j < 4; ++j) acc[i][j] = (f32x4){0.f, 0.f, 0.f, 0.f};

    for (int kt = 0; kt < 32; ++kt) {
        const int k0 = kt * 32;
        __syncthreads();
        gl16(ga + k0, la0);
        gl16(ga + 16 * 1024 + k0, la1);
        gl16(gb + k0, lb0);
        gl16(gb + 16 * 1024 + k0, lb1);
        __syncthreads();
        bf16x8 af[4], bfr[4];
#pragma unroll
        for (int i = 0; i < 4; ++i)
            af[i] = *(const bf16x8*)&lsa[(wm + i * 16 + l15) * 32 + rch];
#pragma unroll
        for (int j = 0; j < 4; ++j)
            bfr[j] = *(const bf16x8*)&lsb[(wn + j * 16 + l15) * 32 + rch];
#pragma unroll
        for (int i = 0; i < 4; ++i)
#pragma unroll
            for (int j = 0; j < 4; ++j)
                acc[i][j] = MFMA16(af[i], bfr[j], acc[i][j], 0, 0, 0);
    }

    const int which = n0 >> 10;
    if (which == 2) {
        // V: write transposed (bh, d, seq); (i,r) axis is seq -> pack 4 bf16.
#pragma unroll
        for (int j = 0; j < 4; ++j) {
            const int n = n0 + wn + j * 16 + l15;
            const int c = n & 1023;
            const int h = c >> 6, d = c & 63;
            const float bv = bias[n];
#pragma unroll
            for (int i = 0; i < 4; ++i) {
                const int m = m0 + wm + i * 16 + quad * 4;   // r=0 row
                const int b = m >> 10, s = m & 1023;
                us4v pk;
#pragma unroll
                for (int r = 0; r < 4; ++r) pk[r] = f2bf(acc[i][j][r] + bv);
                *(us4v*)&vbT[(size_t)((b * 16 + h) * 64 + d) * 1024 + s] = pk;
            }
        }
    } else {
        unsigned short* __restrict__ dst = (which == 0) ? qb : kb;
        const float sc = (which == 0) ? 0.125f : 1.0f;   // q / sqrt(64)
#pragma unroll
        for (int j = 0; j < 4; ++j) {
            const int n = n0 + wn + j * 16 + l15;
            const int c = n & 1023;
            const int h = c >> 6, d = c & 63;
            const float bv = bias[n];
#pragma unroll
            for (int i = 0; i < 4; ++i)
#pragma unroll
                for (int r = 0; r < 4; ++r) {
                    const int m = m0 + wm + i * 16 + quad * 4 + r;
                    const int b = m >> 10, s = m & 1023;
                    const float v = (acc[i][j][r] + bv) * sc;
                    dst[(size_t)((b * 16 + h) * 1024 + s) * 64 + d] = f2bf(v);
                }
        }
    }
}

// ---------------------------------------------------------------------------
// Kernel 2: flash attention, swapped-QK^T form.
//   S^T = MFMA(K_frag, Q_frag): lane (quad,l15) holds S[q=l15][key=quad*4+r]
//   -> float4 mask loads, b64 P^T stores, scalar row-sum, packed O stores.
// 64 q-rows/block, single-buffered, occupancy 4, swizzled K/V panels.
// ---------------------------------------------------------------------------
__global__ __launch_bounds__(256, 4)
void attn_kernel(const unsigned short* __restrict__ qb,
                 const unsigned short* __restrict__ kb,
                 const unsigned short* __restrict__ vbT,  // (bh, d, n)
                 const float* __restrict__ mask,
                 unsigned short* __restrict__ ob)   // (B, N, C) bf16
{
    __shared__ unsigned short lsk0[64 * 32];     // K[seq][d<32]
    __shared__ unsigned short lsk1[64 * 32];     // K[seq][d>=32]
    __shared__ unsigned short lsv0[64 * 32];     // V^T[d][key<32]
    __shared__ unsigned short lsv1[64 * 32];     // V^T[d][key>=32]
    __shared__ unsigned short lsp[4][16 * 72];   // per-wave P^T[q][key] scratch
    const int tid  = threadIdx.x;
    const int wave = tid >> 6, lane = tid & 63;
    const int quad = lane >> 4, l15 = lane & 15;
    const int rch = (quad ^ ((l15 >> 1) & 3)) * 8;   // swizzled read chunk
    const int bh = blockIdx.x >> 4;              // b*16+h
    const int q0 = (blockIdx.x & 15) * 64;
    const int b = bh >> 4, h = bh & 15;

    const unsigned short* __restrict__ kbase = kb + (size_t)bh * 65536;
    const unsigned short* __restrict__ vtb  = vbT + (size_t)bh * 65536;

    const int scol = ((lane & 3) ^ ((lane >> 3) & 3)) * 8;   // swizzled stage
    const unsigned short* gk = kbase + (size_t)(wave * 16 + (lane >> 2)) * 64
                                     + scol;
    const unsigned short* gv = vtb + (size_t)(wave * 16 + (lane >> 2)) * 1024
                                   + scol;
    unsigned short* lk0 = &lsk0[(wave * 16) * 32];
    unsigned short* lk1 = &lsk1[(wave * 16) * 32];
    unsigned short* lv0 = &lsv0[(wave * 16) * 32];
    unsigned short* lv1 = &lsv1[(wave * 16) * 32];

    // Q fragments (B-operand: n = l15 = q, k = quad*8+j = d), q pre-scaled
    bf16x8 bq0, bq1;
    {
        const unsigned short* qrow =
            qb + (size_t)(bh * 1024 + q0 + wave * 16 + l15) * 64;
        bq0 = *(const bf16x8*)(qrow + quad * 8);
        bq1 = *(const bf16x8*)(qrow + 32 + quad * 8);
    }

    float lsum = 0.f;
    f32x4 oacc[4];                 // [nt]: O[q=l15][d=nt*16+quad*4+r]
#pragma unroll
    for (int nt = 0; nt < 4; ++nt) oacc[nt] = (f32x4){0.f, 0.f, 0.f, 0.f};

    const float* __restrict__ mrow =
        mask + (size_t)(q0 + wave * 16 + l15) * 1024;
    unsigned short* lp = lsp[wave];

    for (int kt = 0; kt < 16; ++kt) {
        __syncthreads();
        gl16(gk + (size_t)kt * 4096, lk0);
        gl16(gk + (size_t)kt * 4096 + 32, lk1);
        gl16(gv + (size_t)kt * 64, lv0);
        gl16(gv + (size_t)kt * 64 + 32, lv1);
        __syncthreads();

        // S^T = K Q^T  (C-layout: row=key=quad*4+r, col=q=l15)
        f32x4 s[4];
#pragma unroll
        for (int nt = 0; nt < 4; ++nt) s[nt] = (f32x4){0.f, 0.f, 0.f, 0.f};
#pragma unroll
        for (int nt = 0; nt < 4; ++nt) {
            s[nt] = MFMA16(*(const bf16x8*)&lsk0[(nt * 16 + l15) * 32 + rch],
                           bq0, s[nt], 0, 0, 0);
            s[nt] = MFMA16(*(const bf16x8*)&lsk1[(nt * 16 + l15) * 32 + rch],
                           bq1, s[nt], 0, 0, 0);
        }

        // p = exp(s + mask): float4 mask load, packed P^T store (keys contig)
#pragma unroll
        for (int nt = 0; nt < 4; ++nt) {
            const float4 mv =
                *(const float4*)&mrow[kt * 64 + nt * 16 + quad * 4];
            us4v pk;
#pragma unroll
            for (int r = 0; r < 4; ++r) {
                const float p = __expf(s[nt][r] + ((const float*)&mv)[r]);
                lsum += p;
                pk[r] = f2bf(p);
            }
            *(us4v*)&lp[l15 * 72 + nt * 16 + quad * 4] = pk;
        }
        const bf16x8 pb0 = *(const bf16x8*)&lp[l15 * 72 + quad * 8];
        const bf16x8 pb1 = *(const bf16x8*)&lp[l15 * 72 + 32 + quad * 8];

        // O += P V via O = (V^T as A) x (P^T as B): C row=d, col=q
#pragma unroll
        for (int nt = 0; nt < 4; ++nt) {
            oacc[nt] = MFMA16(*(const bf16x8*)&lsv0[(nt * 16 + l15) * 32 + rch],
                              pb0, oacc[nt], 0, 0, 0);
            oacc[nt] = MFMA16(*(const bf16x8*)&lsv1[(nt * 16 + l15) * 32 + rch],
                              pb1, oacc[nt], 0, 0, 0);
        }
    }

    // row-sum: partial sums live per-quad; reduce across lane bits 4,5
    lsum += __shfl_xor(lsum, 16, 64);
    lsum += __shfl_xor(lsum, 32, 64);
    const float inv = 1.0f / lsum;

    unsigned short* orow =
        ob + (size_t)(b * 1024 + q0 + wave * 16 + l15) * 1024 + h * 64;
#pragma unroll
    for (int nt = 0; nt < 4; ++nt) {
        us4v o;
#pragma unroll
        for (int r = 0; r < 4; ++r) o[r] = f2bf(oacc[nt][r] * inv);
        *(us4v*)&orow[nt * 16 + quad * 4] = o;
    }
}

// ---------------------------------------------------------------------------
// Kernel 3: out = ob(bf16) @ woutb^T + out_b, fp32 to d_out.
// Both operands pre-bf16 -> pure dual global_load_lds (swizzled), no cvt.
// ---------------------------------------------------------------------------
__global__ __launch_bounds__(256, 3)
void out_gemm(const unsigned short* __restrict__ a,   // (8192,1024) bf16
              const unsigned short* __restrict__ wb,  // (1024,1024) bf16
              const float* __restrict__ bias, float* __restrict__ out)
{
    __shared__ unsigned short lsa[128 * 32];
    __shared__ unsigned short lsb[128 * 32];
    const int tid  = threadIdx.x;
    const int wave = tid >> 6, lane = tid & 63;
    const int quad = lane >> 4, l15 = lane & 15;
    const int rch = (quad ^ ((l15 >> 1) & 3)) * 8;
    const int m0 = blockIdx.x * 128, n0 = blockIdx.y * 128;
    const int wm = (wave & 1) * 64, wn = (wave >> 1) * 64;

    const int srow = wave * 32 + (lane >> 2);
    const int scol = ((lane & 3) ^ ((lane >> 3) & 3)) * 8;
    const unsigned short* ga = a + (size_t)(m0 + srow) * 1024 + scol;
    const unsigned short* gb = wb + (size_t)(n0 + srow) * 1024 + scol;
    unsigned short* la0 = &lsa[(wave * 32) * 32];
    unsigned short* la1 = &lsa[(wave * 32 + 16) * 32];
    unsigned short* lb0 = &lsb[(wave * 32) * 32];
    unsigned short* lb1 = &lsb[(wave * 32 + 16) * 32];

    f32x4 acc[4][4];
#pragma unroll
    for (int i = 0; i < 4; ++i)
#pragma unroll
        for (int j = 0; j < 4; ++j) acc[i][j] = (f32x4){0.f, 0.f, 0.f, 0.f};

    for (int kt = 0; kt < 32; ++kt) {
        const int k0 = kt * 32;
        __syncthreads();
        gl16(ga + k0, la0);
        gl16(ga + 16 * 1024 + k0, la1);
        gl16(gb + k0, lb0);
        gl16(gb + 16 * 1024 + k0, lb1);
        __syncthreads();
        bf16x8 af[4], bfr[4];
#pragma unroll
        for (int i = 0; i < 4; ++i)
            af[i] = *(const bf16x8*)&lsa[(wm + i * 16 + l15) * 32 + rch];
#pragma unroll
        for (int j = 0; j < 4; ++j)
            bfr[j] = *(const bf16x8*)&lsb[(wn + j * 16 + l15) * 32 + rch];
#pragma unroll
        for (int i = 0; i < 4; ++i)
#pragma unroll
            for (int j = 0; j < 4; ++j)
                acc[i][j] = MFMA16(af[i], bfr[j], acc[i][j], 0, 0, 0);
    }

#pragma unroll
    for (int j = 0; j < 4; ++j) {
        const int n = n0 + wn + j * 16 + l15;
        const float bv = bias[n];
#pragma unroll
        for (int i = 0; i < 4; ++i)
#pragma unroll
            for (int r = 0; r < 4; ++r) {
                const int m = m0 + wm + i * 16 + quad * 4 + r;
                out[(size_t)m * 1024 + n] = acc[i][j][r] + bv;
            }
    }
}

// ---------------------------------------------------------------------------
extern "C" void kernel_launch(void* const* d_in, const int* in_sizes, int n_in,
                              void* d_out, int out_size, void* d_ws, size_t ws_size,
                              hipStream_t stream) {
    const float* x    = (const float*)d_in[0];   // (8, 1024, 1024)
    const float* mask = (const float*)d_in[1];   // (1024, 1024)
    const float* win  = (const float*)d_in[2];   // (3072, 1024)
    const float* bin  = (const float*)d_in[3];   // (3072)
    const float* wout = (const float*)d_in[4];   // (1024, 1024)
    const float* bout = (const float*)d_in[5];   // (1024)
    float* out = (float*)d_out;                  // (8, 1024, 1024)

    char* ws = (char*)d_ws;
    unsigned short* xb = (unsigned short*)(ws);
    unsigned short* ob = (unsigned short*)(ws);                       // overlays xb
    unsigned short* qb = (unsigned short*)(ws + (size_t)(16 << 20));
    unsigned short* kb = (unsigned short*)(ws + (size_t)(32 << 20));
    unsigned short* vbT = (unsigned short*)(ws + (size_t)(48 << 20));
    unsigned short* winb  = (unsigned short*)d_out;                   // [0, 6M)
    unsigned short* woutb = (unsigned short*)((char*)d_out + (size_t)(6 << 20));

    cvt_bf16<<<dim3(8192), 256, 0, stream>>>(x, xb, 8 * 1024 * 1024 / 4);
    cvt_bf16<<<dim3(3072), 256, 0, stream>>>(win, winb, 3 * 1024 * 1024 / 4);
    cvt_bf16<<<dim3(1024), 256, 0, stream>>>(wout, woutb, 1024 * 1024 / 4);
    qkv_gemm<<<dim3(64, 24), 256, 0, stream>>>(xb, winb, bin, qb, kb, vbT);
    attn_kernel<<<dim3(2048), 256, 0, stream>>>(qb, kb, vbT, mask, ob);
    out_gemm<<<dim3(64, 8), 256, 0, stream>>>(ob, woutb, bout, out);
}